// Round 1
// baseline (79464.301 us; speedup 1.0000x reference)
//
#include <hip/hip_runtime.h>

typedef float  f32x4  __attribute__((ext_vector_type(4)));
typedef __bf16 bf16x8 __attribute__((ext_vector_type(8)));

#define NB 64
#define NT 512
#define ND 256
#define NH 256
#define NL 2
#define NK 3
#define GR 16      // batch rows per group
#define NGRP 4     // 64 / 16

// ws layout (ushort = bf16):
//   Wih [2][768][256]  @ 0        (393216)
//   Whh [2][768][256]  @ 393216
//   Wgt [2][512][512]  @ 786432   (rows 0..255 = Wg, rows 256..511 = Wt)
//   Wu  [2][256][256]  @ 1310720
//   total 1441792 ushorts = 2.88 MB
#define OFF_WHH 393216
#define OFF_WGT 786432
#define OFF_WU  1310720
#define W_TOTAL 1441792

__device__ inline unsigned short f2bu(float f){
  unsigned int u = __builtin_bit_cast(unsigned int, f);
  unsigned int r = u + 0x7fffu + ((u >> 16) & 1u);
  return (unsigned short)(r >> 16);
}
__device__ inline float sigm(float x){ return 1.0f / (1.0f + __expf(-x)); }
__device__ inline float tanhf_(float x){ return 1.0f - 2.0f / (__expf(2.0f * x) + 1.0f); }

#define MFMA(a,b,c) __builtin_amdgcn_mfma_f32_16x16x32_bf16((a),(b),(c),0,0,0)

__global__ void cvt_weights(const float* __restrict__ Wih, const float* __restrict__ Whh,
                            const float* __restrict__ Wg,  const float* __restrict__ Wt,
                            const float* __restrict__ Wu,  unsigned short* __restrict__ ws){
  int i = blockIdx.x * blockDim.x + threadIdx.x;
  if (i < OFF_WHH) {
    ws[i] = f2bu(Wih[i]);
  } else if (i < OFF_WGT) {
    ws[i] = f2bu(Whh[i - OFF_WHH]);
  } else if (i < OFF_WU) {
    int j = i - OFF_WGT;
    int l = j >> 18; int r = (j >> 9) & 511; int k = j & 511;
    float v = (r < 256) ? Wg[(l * 256 + r) * 512 + k]
                        : Wt[(l * 256 + (r - 256)) * 512 + k];
    ws[i] = f2bu(v);
  } else if (i < W_TOTAL) {
    ws[i] = f2bu(Wu[i - OFF_WU]);
  }
}

__global__ __launch_bounds__(1024, 1) void trm_main(
    const float* __restrict__ x,
    const float* __restrict__ bih_g, const float* __restrict__ bhh_g,
    const float* __restrict__ bg_g,  const float* __restrict__ bt_g,
    const float* __restrict__ bu_g,
    const unsigned short* __restrict__ wbf,
    float* __restrict__ out)
{
  // sA: bf16 activations [16 rows][512 cols], XOR-swizzled within each row.
  // cols 0..255 : inp (x_t / out) ; cols 256..511 : h (for GRU) or rh (refine)
  __shared__ alignas(16) unsigned short sA[GR * 512];
  __shared__ float h0s[GR][NH];
  __shared__ float h1s[GR][NH];
  __shared__ float outs[GR][NH];

  const int tid = threadIdx.x;
  const int grp = blockIdx.x;
  const int ln  = tid & 63;
  const int wv  = tid >> 6;       // wave 0..15
  const int m   = ln & 15;        // A-row for loads / weight-row offset
  const int lg  = ln >> 4;        // k-block 0..3
  const int n0  = wv << 4;        // this wave's 16-col strip
  const int c   = n0 + m;         // epilogue column this lane owns

  auto swz = [](int row, int cb){ return (row << 10) + (cb ^ ((row & 7) << 4)); };
  auto ldA = [&](int row, int cb) -> bf16x8 {
    return *reinterpret_cast<const bf16x8*>(reinterpret_cast<const char*>(sA) + swz(row, cb));
  };
  auto ldG = [](const unsigned short* p) -> bf16x8 {
    return *reinterpret_cast<const bf16x8*>(p);
  };

  for (int i = tid; i < GR * NH; i += 1024){
    ((float*)h0s)[i] = 0.f; ((float*)h1s)[i] = 0.f;
  }
  __syncthreads();

  const int rr = tid >> 6;            // staging row
  const int c4 = (tid & 63) << 2;     // staging col (x4 floats)

  for (int t = 0; t < NT; ++t){
    // ---- stage x_t -> sA[:, :256], h0 -> sA[:, 256:512] (bf16, swizzled) ----
    {
      float4 xv = *reinterpret_cast<const float4*>(x + ((size_t)(grp * GR + rr) * NT + t) * ND + c4);
      ushort4 u; u.x = f2bu(xv.x); u.y = f2bu(xv.y); u.z = f2bu(xv.z); u.w = f2bu(xv.w);
      *reinterpret_cast<ushort4*>(reinterpret_cast<char*>(sA) + swz(rr, c4 * 2)) = u;
      float4 hv = *reinterpret_cast<const float4*>(&h0s[rr][c4]);
      ushort4 uh; uh.x = f2bu(hv.x); uh.y = f2bu(hv.y); uh.z = f2bu(hv.z); uh.w = f2bu(hv.w);
      *reinterpret_cast<ushort4*>(reinterpret_cast<char*>(sA) + swz(rr, 512 + c4 * 2)) = uh;
    }
    __syncthreads();

    for (int lyr = 0; lyr < NL; ++lyr){
      float (*hs)[NH] = lyr ? h1s : h0s;

      // ================= GRU =================
      {
        f32x4 aIr{}, aIz{}, aIn{}, aHr{}, aHz{}, aHn{};
        const unsigned short* Wih = wbf + ((size_t)(lyr * 768 + n0 + m)) * 256;
        const unsigned short* Whh = wbf + OFF_WHH + ((size_t)(lyr * 768 + n0 + m)) * 256;
        #pragma unroll 1
        for (int k0 = 0; k0 < 256; k0 += 32){
          int kk = k0 + lg * 8;
          bf16x8 ai = ldA(m, kk * 2);
          bf16x8 ah = ldA(m, 512 + kk * 2);
          bf16x8 b0 = ldG(Wih + kk);
          bf16x8 b1 = ldG(Wih + 256 * 256 + kk);
          bf16x8 b2 = ldG(Wih + 512 * 256 + kk);
          bf16x8 b3 = ldG(Whh + kk);
          bf16x8 b4 = ldG(Whh + 256 * 256 + kk);
          bf16x8 b5 = ldG(Whh + 512 * 256 + kk);
          aIr = MFMA(ai, b0, aIr);
          aIz = MFMA(ai, b1, aIz);
          aIn = MFMA(ai, b2, aIn);
          aHr = MFMA(ah, b3, aHr);
          aHz = MFMA(ah, b4, aHz);
          aHn = MFMA(ah, b5, aHn);
        }
        float bir = bih_g[lyr * 768 + c],       bhr = bhh_g[lyr * 768 + c];
        float biz = bih_g[lyr * 768 + 256 + c], bhz = bhh_g[lyr * 768 + 256 + c];
        float bin = bih_g[lyr * 768 + 512 + c], bhn = bhh_g[lyr * 768 + 512 + c];
        __syncthreads();   // all k-loop reads of sA done before we overwrite it
        #pragma unroll
        for (int j = 0; j < 4; ++j){
          int row = lg * 4 + j;          // C/D row = batch row
          float r  = sigm(aIr[j] + aHr[j] + bir + bhr);
          float z  = sigm(aIz[j] + aHz[j] + biz + bhz);
          float nn = tanhf_(aIn[j] + bin + r * (aHn[j] + bhn));
          float hold = hs[row][c];
          float hnew = (1.f - z) * nn + z * hold;
          hs[row][c]   = hnew;
          outs[row][c] = hnew;
          unsigned short hb = f2bu(hnew);
          *(unsigned short*)((char*)sA + swz(row, c * 2))         = hb;  // out = h_new
          *(unsigned short*)((char*)sA + swz(row, (256 + c) * 2)) = hb;  // rh  = h_new
        }
        __syncthreads();
      }

      // ================= refinement (K=3) =================
      const float* bgp = bg_g + lyr * NH;
      const float* btp = bt_g + lyr * NH;
      const float* bup = bu_g + lyr * NH;
      const unsigned short* Wgt = wbf + OFF_WGT + (size_t)lyr * 512 * 512;
      const unsigned short* Wu  = wbf + OFF_WU  + (size_t)lyr * 256 * 256;

      for (int it = 0; it < NK; ++it){
        // --- g/ref: [out|rh](16x512) @ Wgt^T -> wave's cols n0 (g) & n0+256 (ref)
        f32x4 ag{}, ar{};
        const unsigned short* pg = Wgt + ((size_t)(n0 + m)) * 512;
        const unsigned short* pr = Wgt + ((size_t)(256 + n0 + m)) * 512;
        #pragma unroll 2
        for (int k0 = 0; k0 < 512; k0 += 32){
          int kk = k0 + lg * 8;
          bf16x8 a = ldA(m, kk * 2);
          ag = MFMA(a, ldG(pg + kk), ag);
          ar = MFMA(a, ldG(pr + kk), ar);
        }
        float bgv = bgp[c], btv = btp[c];
        __syncthreads();
        #pragma unroll
        for (int j = 0; j < 4; ++j){
          int row = lg * 4 + j;
          float g  = sigm(ag[j] + bgv);
          float rf = tanhf_(ar[j] + btv);
          float oo = outs[row][c];
          float on = g * rf + (1.f - g) * oo;
          outs[row][c] = on;
          *(unsigned short*)((char*)sA + swz(row, c * 2)) = f2bu(on);
        }
        __syncthreads();

        if (it < NK - 1){
          // --- rh = tanh(out @ Wu^T + bu): reads sA[:, :256], writes sA[:, 256:]
          f32x4 au{};
          const unsigned short* pu = Wu + ((size_t)(n0 + m)) * 256;
          #pragma unroll 2
          for (int k0 = 0; k0 < 256; k0 += 32){
            int kk = k0 + lg * 8;
            au = MFMA(ldA(m, kk * 2), ldG(pu + kk), au);
          }
          float buv = bup[c];
          #pragma unroll
          for (int j = 0; j < 4; ++j){
            int row = lg * 4 + j;
            *(unsigned short*)((char*)sA + swz(row, (256 + c) * 2)) = f2bu(tanhf_(au[j] + buv));
          }
          __syncthreads();  // disjoint halves: only need this one before next g/ref
        }
      }

      if (lyr == 0){
        // prepare layer 1: sA[:, :256] already = out^0; restage h1 into sA[:, 256:]
        float4 hv = *reinterpret_cast<const float4*>(&h1s[rr][c4]);
        ushort4 u; u.x = f2bu(hv.x); u.y = f2bu(hv.y); u.z = f2bu(hv.z); u.w = f2bu(hv.w);
        *reinterpret_cast<ushort4*>(reinterpret_cast<char*>(sA) + swz(rr, 512 + c4 * 2)) = u;
        __syncthreads();
      } else {
        // emit output[b][t][:] = layer-1 refined out (f32)
        float4 ov = *reinterpret_cast<const float4*>(&outs[rr][c4]);
        *reinterpret_cast<float4*>(out + ((size_t)(grp * GR + rr) * NT + t) * NH + c4) = ov;
      }
    } // lyr
  } // t

  // final_hidden (L, B, H) at offset B*T*H
  {
    const size_t FH = (size_t)NB * NT * NH;
    float4 a0 = *reinterpret_cast<const float4*>(&h0s[rr][c4]);
    float4 a1 = *reinterpret_cast<const float4*>(&h1s[rr][c4]);
    *reinterpret_cast<float4*>(out + FH + (size_t)(grp * GR + rr) * NH + c4) = a0;
    *reinterpret_cast<float4*>(out + FH + (size_t)NB * NH + (size_t)(grp * GR + rr) * NH + c4) = a1;
  }
}

extern "C" void kernel_launch(void* const* d_in, const int* in_sizes, int n_in,
                              void* d_out, int out_size, void* d_ws, size_t ws_size,
                              hipStream_t stream) {
  const float* x   = (const float*)d_in[0];
  const float* Wih = (const float*)d_in[1];
  const float* bih = (const float*)d_in[2];
  const float* Whh = (const float*)d_in[3];
  const float* bhh = (const float*)d_in[4];
  const float* Wg  = (const float*)d_in[5];
  const float* bg  = (const float*)d_in[6];
  const float* Wt  = (const float*)d_in[7];
  const float* bt  = (const float*)d_in[8];
  const float* Wu  = (const float*)d_in[9];
  const float* bu  = (const float*)d_in[10];
  unsigned short* ws = (unsigned short*)d_ws;
  float* o = (float*)d_out;

  cvt_weights<<<W_TOTAL / 256, 256, 0, stream>>>(Wih, Whh, Wg, Wt, Wu, ws);
  trm_main<<<NGRP, 1024, 0, stream>>>(x, bih, bhh, bg, bt, bu, ws, o);
}

// Round 2
// 4971.824 us; speedup vs baseline: 15.9829x; 15.9829x over previous
//
#include <hip/hip_runtime.h>

typedef float  f32x4  __attribute__((ext_vector_type(4)));
typedef __bf16 bf16x8 __attribute__((ext_vector_type(8)));

#define NB 64
#define NT 512
#define ND 256
#define NH 256
#define NROW (NB*NT)   // 32768

// ws ushort offsets
#define OFF_WIH 0
#define OFF_WHH 393216
#define OFF_WGT 786432          // [l][512][512]: rows 0-255 Wg, 256-511 Wt (K = [out|rh])
#define OFF_WU  1310720
#define W_TOTAL 1441792
#define OFF_XIN (W_TOTAL)                   // [32768][256] bf16  (x)
#define OFF_GI  (OFF_XIN + NROW*256)        // [512][64][768] bf16, t-major
#define OFF_OUT (OFF_GI + 512*64*768)       // [32768][256] bf16
#define OFF_RH  (OFF_OUT + NROW*256)        // [32768][256] bf16
// total = 51,773,440 ushorts = 103.5 MB

__device__ inline unsigned short f2bu(float f){
  unsigned int u = __builtin_bit_cast(unsigned int, f);
  unsigned int r = u + 0x7fffu + ((u >> 16) & 1u);
  return (unsigned short)(r >> 16);
}
__device__ inline float bf2f(unsigned short u){
  unsigned int v = ((unsigned int)u) << 16;
  return __builtin_bit_cast(float, v);
}
__device__ inline float sigm(float x){ return 1.0f / (1.0f + __expf(-x)); }
__device__ inline float tanhf_(float x){ return 1.0f - 2.0f / (__expf(2.0f * x) + 1.0f); }

#define MFMA(a,b,c) __builtin_amdgcn_mfma_f32_16x16x32_bf16((a),(b),(c),0,0,0)

__device__ inline void gload_lds16(const void* g, void* l){
  __builtin_amdgcn_global_load_lds(
    (const __attribute__((address_space(1))) unsigned int*)g,
    (__attribute__((address_space(3))) unsigned int*)l, 16, 0, 0);
}
__device__ inline bf16x8 ldG(const unsigned short* p){
  return *reinterpret_cast<const bf16x8*>(p);
}

// ---------------- weight / input packing ----------------
__global__ void cvt_weights(const float* __restrict__ Wih, const float* __restrict__ Whh,
                            const float* __restrict__ Wg,  const float* __restrict__ Wt,
                            const float* __restrict__ Wu,  unsigned short* __restrict__ ws){
  int i = blockIdx.x * blockDim.x + threadIdx.x;
  if (i < OFF_WHH) {
    ws[i] = f2bu(Wih[i]);
  } else if (i < OFF_WGT) {
    ws[i] = f2bu(Whh[i - OFF_WHH]);
  } else if (i < OFF_WU) {
    int j = i - OFF_WGT;
    int l = j >> 18; int r = (j >> 9) & 511; int k = j & 511;
    float v = (r < 256) ? Wg[(l * 256 + r) * 512 + k]
                        : Wt[(l * 256 + (r - 256)) * 512 + k];
    ws[i] = f2bu(v);
  } else if (i < W_TOTAL) {
    ws[i] = f2bu(Wu[i - OFF_WU]);
  }
}

__global__ void pack_x(const float* __restrict__ x, unsigned short* __restrict__ xin){
  size_t i = ((size_t)blockIdx.x * blockDim.x + threadIdx.x) * 4;
  float4 v = *reinterpret_cast<const float4*>(x + i);
  ushort4 u; u.x = f2bu(v.x); u.y = f2bu(v.y); u.z = f2bu(v.z); u.w = f2bu(v.w);
  *reinterpret_cast<ushort4*>(xin + i) = u;
}

// ---------------- GI = in @ Wih^T + bih  (parallel over all rows) ----------------
__global__ __launch_bounds__(1024) void gi_gemm(
    const unsigned short* __restrict__ xin,  // [NROW][256] bf16
    const unsigned short* __restrict__ wih,  // [768][256] bf16 (layer slice)
    const float* __restrict__ bih,           // [768]
    unsigned short* __restrict__ gi)         // [512][64][768] bf16 (t-major)
{
  __shared__ alignas(16) unsigned short sA[64 * 256];
  const int tid = threadIdx.x, blk = blockIdx.x;
  const int ln = tid & 63, wv = tid >> 6, m = ln & 15, lg = ln >> 4;
  {
    const char* src = (const char*)(xin + (size_t)blk * 64 * 256);
    #pragma unroll
    for (int i = 0; i < 2; ++i){
      int o = tid * 16 + i * 16384;
      int r = o >> 9, wb = o & 511;
      gload_lds16(src + (size_t)r * 512 + (wb ^ ((r & 7) << 4)), (char*)sA + o);
    }
  }
  __syncthreads();
  f32x4 acc[3][4] = {};
  #pragma unroll
  for (int kc = 0; kc < 8; ++kc){
    int kk = kc * 32 + lg * 8;
    bf16x8 a[4];
    #pragma unroll
    for (int mt = 0; mt < 4; ++mt){
      int row = mt * 16 + m;
      a[mt] = *(const bf16x8*)((const char*)sA + row * 512 + ((kk * 2) ^ ((row & 7) << 4)));
    }
    #pragma unroll
    for (int g = 0; g < 3; ++g){
      bf16x8 b = ldG(wih + (size_t)(g * 256 + wv * 16 + m) * 256 + kk);
      #pragma unroll
      for (int mt = 0; mt < 4; ++mt) acc[g][mt] = MFMA(a[mt], b, acc[g][mt]);
    }
  }
  const int c = wv * 16 + m;
  #pragma unroll
  for (int g = 0; g < 3; ++g){
    float bias = bih[g * 256 + c];
    #pragma unroll
    for (int mt = 0; mt < 4; ++mt){
      #pragma unroll
      for (int j = 0; j < 4; ++j){
        int row = blk * 64 + mt * 16 + lg * 4 + j;
        int b = row >> 9, t = row & 511;
        gi[((size_t)t * 64 + b) * 768 + g * 256 + c] = f2bu(acc[g][mt][j] + bias);
      }
    }
  }
}

// ---------------- sequential GRU chain (per layer) ----------------
// grid 4 (batch groups of 16), block 512 (8 waves). r,z weights register-resident,
// n-gate streamed; GI[t+1] prefetched to LDS; h in registers; 1 barrier/step.
__global__ __launch_bounds__(512, 2) void chain(
    const unsigned short* __restrict__ gi,   // [512][64][768]
    const unsigned short* __restrict__ whh,  // [768][256] layer slice
    const float* __restrict__ bhh,           // [768]
    unsigned short* __restrict__ outw,       // [NROW][256]
    unsigned short* __restrict__ rhw,        // [NROW][256]
    float* __restrict__ hfin)                // [64][256] final hidden (this layer)
{
  __shared__ alignas(16) unsigned short hA[2][16 * 256];   // h bf16, swizzled 512B rows
  __shared__ alignas(16) unsigned short sGI[2][16 * 768];  // gi slice, linear
  const int tid = threadIdx.x, grp = blockIdx.x;
  const int ln = tid & 63, wv = tid >> 6, m = ln & 15, lg = ln >> 4;

  // resident r,z weight fragments: cols wv*32 + tt*16 + m
  bf16x8 wr[2][8], wz[2][8];
  #pragma unroll
  for (int tt = 0; tt < 2; ++tt){
    const unsigned short* pr = whh + (size_t)(0 * 256 + wv * 32 + tt * 16 + m) * 256;
    const unsigned short* pz = whh + (size_t)(1 * 256 + wv * 32 + tt * 16 + m) * 256;
    #pragma unroll
    for (int kc = 0; kc < 8; ++kc){
      wr[tt][kc] = ldG(pr + kc * 32 + lg * 8);
      wz[tt][kc] = ldG(pz + kc * 32 + lg * 8);
    }
  }
  float bR[2], bZ[2], bN[2];
  #pragma unroll
  for (int tt = 0; tt < 2; ++tt){
    int c = wv * 32 + tt * 16 + m;
    bR[tt] = bhh[c]; bZ[tt] = bhh[256 + c]; bN[tt] = bhh[512 + c];
  }
  // zero h staging buf 0 (8192 B, 512 threads x 16B)
  *reinterpret_cast<uint4*>((char*)hA[0] + tid * 16) = uint4{0, 0, 0, 0};
  // stage GI[0]
  {
    const char* g0 = (const char*)gi + ((size_t)0 * 64 + grp * 16) * 768 * 2;
    #pragma unroll
    for (int i = 0; i < 3; ++i)
      gload_lds16(g0 + tid * 16 + i * 8192, (char*)sGI[0] + tid * 16 + i * 8192);
  }
  float hreg[2][4] = {};
  __syncthreads();

  for (int t = 0; t < NT; ++t){
    const int cur = t & 1, nxt = cur ^ 1;
    if (t + 1 < NT){
      const char* gs = (const char*)gi + ((size_t)(t + 1) * 64 + grp * 16) * 768 * 2;
      #pragma unroll
      for (int i = 0; i < 3; ++i)
        gload_lds16(gs + tid * 16 + i * 8192, (char*)sGI[nxt] + tid * 16 + i * 8192);
    }
    f32x4 aR[2] = {}, aZ[2] = {}, aN[2] = {};
    #pragma unroll
    for (int kc = 0; kc < 8; ++kc){
      int kk = kc * 32 + lg * 8;
      bf16x8 a = *(const bf16x8*)((const char*)hA[cur] + m * 512 + ((kk * 2) ^ ((m & 7) << 4)));
      #pragma unroll
      for (int tt = 0; tt < 2; ++tt){
        bf16x8 bn = ldG(whh + (size_t)(512 + wv * 32 + tt * 16 + m) * 256 + kk);
        aR[tt] = MFMA(a, wr[tt][kc], aR[tt]);
        aZ[tt] = MFMA(a, wz[tt][kc], aZ[tt]);
        aN[tt] = MFMA(a, bn, aN[tt]);
      }
    }
    #pragma unroll
    for (int tt = 0; tt < 2; ++tt){
      int c = wv * 32 + tt * 16 + m;
      #pragma unroll
      for (int j = 0; j < 4; ++j){
        int rowl = lg * 4 + j;
        float gr = bf2f(sGI[cur][rowl * 768 + c]);
        float gz = bf2f(sGI[cur][rowl * 768 + 256 + c]);
        float gn = bf2f(sGI[cur][rowl * 768 + 512 + c]);
        float r  = sigm(aR[tt][j] + bR[tt] + gr);
        float z  = sigm(aZ[tt][j] + bZ[tt] + gz);
        float nn = tanhf_(gn + r * (aN[tt][j] + bN[tt]));
        float hnew = (1.f - z) * nn + z * hreg[tt][j];
        hreg[tt][j] = hnew;
        unsigned short hb = f2bu(hnew);
        *(unsigned short*)((char*)hA[nxt] + rowl * 512 + ((c * 2) ^ ((rowl & 7) << 4))) = hb;
        size_t go = ((size_t)(grp * 16 + rowl) * NT + t) * 256 + c;
        outw[go] = hb;
        rhw[go]  = hb;
        if (t == NT - 1) hfin[(size_t)(grp * 16 + rowl) * 256 + c] = hnew;
      }
    }
    __syncthreads();
  }
}

// ---------------- refinement stage A: g/ref + out update ----------------
template<int FINAL>
__global__ __launch_bounds__(1024) void refineA(
    const unsigned short* __restrict__ outb, const unsigned short* __restrict__ rhb,
    const unsigned short* __restrict__ wgt,  // [512][512] layer slice
    const float* __restrict__ bg, const float* __restrict__ bt,
    unsigned short* __restrict__ outw, float* __restrict__ dst)
{
  __shared__ alignas(16) unsigned short sC[64 * 512];   // comb [64][512], 1024B rows swizzled
  const int tid = threadIdx.x, blk = blockIdx.x;
  const int ln = tid & 63, wv = tid >> 6, m = ln & 15, lg = ln >> 4;
  {
    #pragma unroll
    for (int i = 0; i < 4; ++i){
      int o = tid * 16 + i * 16384;
      int r = o >> 10, wb = o & 1023;
      int wb2 = wb ^ ((r & 7) << 4);
      const char* src = (wb2 < 512)
        ? (const char*)(outb + (size_t)(blk * 64 + r) * 256) + wb2
        : (const char*)(rhb  + (size_t)(blk * 64 + r) * 256) + (wb2 - 512);
      gload_lds16(src, (char*)sC + o);
    }
  }
  __syncthreads();
  f32x4 ag[4] = {}, at[4] = {};
  #pragma unroll 2
  for (int kc = 0; kc < 16; ++kc){
    int kk = kc * 32 + lg * 8;
    bf16x8 a[4];
    #pragma unroll
    for (int mt = 0; mt < 4; ++mt){
      int row = mt * 16 + m;
      a[mt] = *(const bf16x8*)((const char*)sC + row * 1024 + ((kk * 2) ^ ((row & 7) << 4)));
    }
    bf16x8 bgf = ldG(wgt + (size_t)(wv * 16 + m) * 512 + kk);
    bf16x8 btf = ldG(wgt + (size_t)(256 + wv * 16 + m) * 512 + kk);
    #pragma unroll
    for (int mt = 0; mt < 4; ++mt){
      ag[mt] = MFMA(a[mt], bgf, ag[mt]);
      at[mt] = MFMA(a[mt], btf, at[mt]);
    }
  }
  const int c = wv * 16 + m;
  float bgv = bg[c], btv = bt[c];
  #pragma unroll
  for (int mt = 0; mt < 4; ++mt){
    #pragma unroll
    for (int j = 0; j < 4; ++j){
      int rowl = mt * 16 + lg * 4 + j;
      float g  = sigm(ag[mt][j] + bgv);
      float rf = tanhf_(at[mt][j] + btv);
      float old = bf2f(sC[(rowl * 1024 + ((c * 2) ^ ((rowl & 7) << 4))) >> 1]);
      float on = g * rf + (1.f - g) * old;
      size_t go = (size_t)(blk * 64 + rowl) * 256 + c;
      if (FINAL) dst[go] = on;
      else       outw[go] = f2bu(on);
    }
  }
}

// ---------------- refinement stage B: rh = tanh(out @ Wu^T + bu) ----------------
__global__ __launch_bounds__(1024) void refineB(
    const unsigned short* __restrict__ outb, const unsigned short* __restrict__ wu,
    const float* __restrict__ bu, unsigned short* __restrict__ rhw)
{
  __shared__ alignas(16) unsigned short sA[64 * 256];
  const int tid = threadIdx.x, blk = blockIdx.x;
  const int ln = tid & 63, wv = tid >> 6, m = ln & 15, lg = ln >> 4;
  {
    const char* src = (const char*)(outb + (size_t)blk * 64 * 256);
    #pragma unroll
    for (int i = 0; i < 2; ++i){
      int o = tid * 16 + i * 16384;
      int r = o >> 9, wb = o & 511;
      gload_lds16(src + (size_t)r * 512 + (wb ^ ((r & 7) << 4)), (char*)sA + o);
    }
  }
  __syncthreads();
  f32x4 acc[4] = {};
  #pragma unroll
  for (int kc = 0; kc < 8; ++kc){
    int kk = kc * 32 + lg * 8;
    bf16x8 b = ldG(wu + (size_t)(wv * 16 + m) * 256 + kk);
    #pragma unroll
    for (int mt = 0; mt < 4; ++mt){
      int row = mt * 16 + m;
      bf16x8 a = *(const bf16x8*)((const char*)sA + row * 512 + ((kk * 2) ^ ((row & 7) << 4)));
      acc[mt] = MFMA(a, b, acc[mt]);
    }
  }
  const int c = wv * 16 + m;
  float buv = bu[c];
  #pragma unroll
  for (int mt = 0; mt < 4; ++mt){
    #pragma unroll
    for (int j = 0; j < 4; ++j){
      int rowl = mt * 16 + lg * 4 + j;
      rhw[(size_t)(blk * 64 + rowl) * 256 + c] = f2bu(tanhf_(acc[mt][j] + buv));
    }
  }
}

extern "C" void kernel_launch(void* const* d_in, const int* in_sizes, int n_in,
                              void* d_out, int out_size, void* d_ws, size_t ws_size,
                              hipStream_t stream) {
  const float* x   = (const float*)d_in[0];
  const float* Wih = (const float*)d_in[1];
  const float* bih = (const float*)d_in[2];
  const float* Whh = (const float*)d_in[3];
  const float* bhh = (const float*)d_in[4];
  const float* Wg  = (const float*)d_in[5];
  const float* bg  = (const float*)d_in[6];
  const float* Wt  = (const float*)d_in[7];
  const float* bt  = (const float*)d_in[8];
  const float* Wu  = (const float*)d_in[9];
  const float* bu  = (const float*)d_in[10];
  unsigned short* ws = (unsigned short*)d_ws;
  float* o  = (float*)d_out;
  float* hf = o + (size_t)NB * NT * NH;

  unsigned short* xin  = ws + OFF_XIN;
  unsigned short* gi   = ws + OFF_GI;
  unsigned short* outb = ws + OFF_OUT;
  unsigned short* rhb  = ws + OFF_RH;

  cvt_weights<<<W_TOTAL / 256, 256, 0, stream>>>(Wih, Whh, Wg, Wt, Wu, ws);
  pack_x<<<(NROW * 256 / 4) / 256, 256, 0, stream>>>(x, xin);

  for (int l = 0; l < 2; ++l){
    const unsigned short* wih = ws + OFF_WIH + (size_t)l * 768 * 256;
    const unsigned short* whh = ws + OFF_WHH + (size_t)l * 768 * 256;
    const unsigned short* wgt = ws + OFF_WGT + (size_t)l * 512 * 512;
    const unsigned short* wu  = ws + OFF_WU  + (size_t)l * 256 * 256;

    gi_gemm<<<512, 1024, 0, stream>>>(l == 0 ? xin : outb, wih, bih + l * 768, gi);
    chain<<<4, 512, 0, stream>>>(gi, whh, bhh + l * 768, outb, rhb, hf + (size_t)l * NB * NH);
    refineA<0><<<512, 1024, 0, stream>>>(outb, rhb, wgt, bg + l * 256, bt + l * 256, outb, nullptr);
    refineB<<<512, 1024, 0, stream>>>(outb, wu, bu + l * 256, rhb);
    refineA<0><<<512, 1024, 0, stream>>>(outb, rhb, wgt, bg + l * 256, bt + l * 256, outb, nullptr);
    refineB<<<512, 1024, 0, stream>>>(outb, wu, bu + l * 256, rhb);
    if (l == 0)
      refineA<0><<<512, 1024, 0, stream>>>(outb, rhb, wgt, bg + l * 256, bt + l * 256, outb, nullptr);
    else
      refineA<1><<<512, 1024, 0, stream>>>(outb, rhb, wgt, bg + l * 256, bt + l * 256, nullptr, o);
  }
}

// Round 3
// 2995.395 us; speedup vs baseline: 26.5288x; 1.6598x over previous
//
#include <hip/hip_runtime.h>

typedef float  f32x4  __attribute__((ext_vector_type(4)));
typedef __bf16 bf16x8 __attribute__((ext_vector_type(8)));

#define NB 64
#define NT 512
#define ND 256
#define NH 256
#define NROW (NB*NT)   // 32768

// ws ushort offsets
#define OFF_WIH 0
#define OFF_WHH 393216
#define OFF_WGT 786432          // [l][512][512]: rows 0-255 Wg, 256-511 Wt
#define OFF_WU  1310720
#define W_TOTAL 1441792
#define OFF_XIN (W_TOTAL)                   // [32768][256] bf16 (b-major)
#define OFF_GI  (OFF_XIN + NROW*256)        // [512][64][768] bf16, t-major
#define OFF_OUT (OFF_GI + 512*64*768)       // [32768][256] bf16
#define OFF_RH  (OFF_OUT + NROW*256)        // [32768][256] bf16

__device__ inline unsigned short f2bu(float f){
  unsigned int u = __builtin_bit_cast(unsigned int, f);
  unsigned int r = u + 0x7fffu + ((u >> 16) & 1u);
  return (unsigned short)(r >> 16);
}
__device__ inline float bf2f(unsigned short u){
  unsigned int v = ((unsigned int)u) << 16;
  return __builtin_bit_cast(float, v);
}
__device__ inline float sigm(float x){ return 1.0f / (1.0f + __expf(-x)); }
__device__ inline float tanhf_(float x){ return 1.0f - 2.0f / (__expf(2.0f * x) + 1.0f); }

#define MFMA(a,b,c) __builtin_amdgcn_mfma_f32_16x16x32_bf16((a),(b),(c),0,0,0)

__device__ inline void gload_lds16(const void* g, void* l){
  __builtin_amdgcn_global_load_lds(
    (const __attribute__((address_space(1))) unsigned int*)g,
    (__attribute__((address_space(3))) unsigned int*)l, 16, 0, 0);
}
__device__ inline bf16x8 ldG(const unsigned short* p){
  return *reinterpret_cast<const bf16x8*>(p);
}

// ---------------- weight / input packing ----------------
__global__ void cvt_weights(const float* __restrict__ Wih, const float* __restrict__ Whh,
                            const float* __restrict__ Wg,  const float* __restrict__ Wt,
                            const float* __restrict__ Wu,  unsigned short* __restrict__ ws){
  int i = blockIdx.x * blockDim.x + threadIdx.x;
  if (i < OFF_WHH) {
    ws[i] = f2bu(Wih[i]);
  } else if (i < OFF_WGT) {
    ws[i] = f2bu(Whh[i - OFF_WHH]);
  } else if (i < OFF_WU) {
    int j = i - OFF_WGT;
    int l = j >> 18; int r = (j >> 9) & 511; int k = j & 511;
    float v = (r < 256) ? Wg[(l * 256 + r) * 512 + k]
                        : Wt[(l * 256 + (r - 256)) * 512 + k];
    ws[i] = f2bu(v);
  } else if (i < W_TOTAL) {
    ws[i] = f2bu(Wu[i - OFF_WU]);
  }
}

__global__ void pack_x(const float* __restrict__ x, unsigned short* __restrict__ xin){
  size_t i = ((size_t)blockIdx.x * blockDim.x + threadIdx.x) * 4;
  float4 v = *reinterpret_cast<const float4*>(x + i);
  ushort4 u; u.x = f2bu(v.x); u.y = f2bu(v.y); u.z = f2bu(v.z); u.w = f2bu(v.w);
  *reinterpret_cast<ushort4*>(xin + i) = u;
}

// ---------------- GI = in @ Wih^T + (bih [+ bhh for r,z]) ----------------
__global__ __launch_bounds__(1024) void gi_gemm(
    const unsigned short* __restrict__ xin,  // [NROW][256] bf16 (b-major)
    const unsigned short* __restrict__ wih,  // [768][256]
    const float* __restrict__ bih, const float* __restrict__ bhh,
    unsigned short* __restrict__ gi)         // [512][64][768] t-major
{
  __shared__ alignas(16) unsigned short sA[64 * 256];
  const int tid = threadIdx.x, blk = blockIdx.x;
  const int ln = tid & 63, wv = tid >> 6, m = ln & 15, lg = ln >> 4;
  {
    const char* src = (const char*)(xin + (size_t)blk * 64 * 256);
    #pragma unroll
    for (int i = 0; i < 2; ++i){
      int o = tid * 16 + i * 16384;
      int r = o >> 9, wb = o & 511;
      gload_lds16(src + (size_t)r * 512 + (wb ^ ((r & 7) << 4)), (char*)sA + o);
    }
  }
  __syncthreads();
  f32x4 acc[3][4] = {};
  #pragma unroll
  for (int kc = 0; kc < 8; ++kc){
    int kk = kc * 32 + lg * 8;
    bf16x8 a[4];
    #pragma unroll
    for (int mt = 0; mt < 4; ++mt){
      int row = mt * 16 + m;
      a[mt] = *(const bf16x8*)((const char*)sA + row * 512 + ((kk * 2) ^ ((row & 7) << 4)));
    }
    #pragma unroll
    for (int g = 0; g < 3; ++g){
      bf16x8 b = ldG(wih + (size_t)(g * 256 + wv * 16 + m) * 256 + kk);
      #pragma unroll
      for (int mt = 0; mt < 4; ++mt) acc[g][mt] = MFMA(a[mt], b, acc[g][mt]);
    }
  }
  const int c = wv * 16 + m;
  #pragma unroll
  for (int g = 0; g < 3; ++g){
    float bias = bih[g * 256 + c] + (g < 2 ? bhh[g * 256 + c] : 0.f);
    #pragma unroll
    for (int mt = 0; mt < 4; ++mt){
      #pragma unroll
      for (int j = 0; j < 4; ++j){
        int row = blk * 64 + mt * 16 + lg * 4 + j;
        int b = row >> 9, t = row & 511;
        gi[((size_t)t * 64 + b) * 768 + g * 256 + c] = f2bu(acc[g][mt][j] + bias);
      }
    }
  }
}

// ---------------- sequential GRU chain ----------------
// grid 8 (8 batch rows each), block 512 (8 waves). ALL of Whh register-resident
// (192 VGPR/lane). Vectorized epilogue; 2 barriers/step.
__global__ __launch_bounds__(512, 2) void chain(
    const unsigned short* __restrict__ gi,   // [512][64][768]
    const unsigned short* __restrict__ whh,  // [768][256]
    const float* __restrict__ bhh,           // [768] (n-part used)
    unsigned short* __restrict__ outw, unsigned short* __restrict__ rhw,
    float* __restrict__ hfin)                // [64][256] this layer
{
  __shared__ alignas(16) unsigned short hA[2][16 * 256];    // 8KB each, 512B rows swizzled
  __shared__ alignas(16) unsigned short sGI[2][8 * 768];    // 12KB each
  __shared__ alignas(16) float sG[8 * 768];                 // 24KB
  const int tid = threadIdx.x, grp = blockIdx.x;
  const int ln = tid & 63, wv = tid >> 6, m = ln & 15, lg = ln >> 4;

  // resident weights: 6 tiles x 8 k-chunks (as f32x4 to pin; bitcast at use)
  f32x4 wf[6][8];
  #pragma unroll
  for (int tt = 0; tt < 6; ++tt){
    const unsigned short* p = whh + (size_t)(wv * 96 + tt * 16 + m) * 256;
    #pragma unroll
    for (int kc = 0; kc < 8; ++kc){
      wf[tt][kc] = *reinterpret_cast<const f32x4*>(p + kc * 32 + lg * 8);
      asm volatile("" : "+v"(wf[tt][kc]));
    }
  }
  // epilogue layout: row er (one per wave), cols ec..ec+3
  const int er = tid >> 6;
  const int ec = ln * 4;
  f32x4 bN = *reinterpret_cast<const f32x4*>(bhh + 512 + ec);
  f32x4 h = {0.f, 0.f, 0.f, 0.f};
  *reinterpret_cast<uint4*>((char*)hA[0] + tid * 16) = uint4{0,0,0,0};
  *reinterpret_cast<uint4*>((char*)hA[1] + tid * 16) = uint4{0,0,0,0};
  {
    const char* g0 = (const char*)gi + ((size_t)(0 * 64) + grp * 8) * 1536;
    gload_lds16(g0 + tid * 16, (char*)sGI[0] + tid * 16);
    if (tid < 256) gload_lds16(g0 + 8192 + tid * 16, (char*)sGI[0] + 8192 + tid * 16);
  }
  __syncthreads();

  for (int t = 0; t < NT; ++t){
    const int cur = t & 1, nxt = cur ^ 1;
    f32x4 acc[6] = {};
    #pragma unroll
    for (int kc = 0; kc < 8; ++kc){
      int kb = kc * 64 + lg * 16;   // byte offset within 512B row
      bf16x8 a = *(const bf16x8*)((const char*)hA[cur] + m * 512 + (kb ^ ((m & 7) << 4)));
      #pragma unroll
      for (int tt = 0; tt < 6; ++tt)
        acc[tt] = MFMA(a, __builtin_bit_cast(bf16x8, wf[tt][kc]), acc[tt]);
    }
    // write pre-activations (valid rows 0..7 live in lanes lg<2)
    if (lg < 2){
      #pragma unroll
      for (int tt = 0; tt < 6; ++tt){
        int c = wv * 96 + tt * 16 + m;
        #pragma unroll
        for (int j = 0; j < 4; ++j)
          sG[(lg * 4 + j) * 768 + c] = acc[tt][j];
      }
    }
    __syncthreads();   // barrier 1: preacts visible

    // prefetch GI[t+1] (drained by barrier 2)
    if (t + 1 < NT){
      const char* gs = (const char*)gi + ((size_t)(t + 1) * 64 + grp * 8) * 1536;
      gload_lds16(gs + tid * 16, (char*)sGI[nxt] + tid * 16);
      if (tid < 256) gload_lds16(gs + 8192 + tid * 16, (char*)sGI[nxt] + 8192 + tid * 16);
    }

    // vectorized epilogue: thread owns (er, ec..ec+3)
    {
      ushort4 ur = *(const ushort4*)(&sGI[cur][er * 768 + ec]);
      ushort4 uz = *(const ushort4*)(&sGI[cur][er * 768 + 256 + ec]);
      ushort4 un = *(const ushort4*)(&sGI[cur][er * 768 + 512 + ec]);
      f32x4 sR = *(const f32x4*)(&sG[er * 768 + ec]);
      f32x4 sZ = *(const f32x4*)(&sG[er * 768 + 256 + ec]);
      f32x4 sN = *(const f32x4*)(&sG[er * 768 + 512 + ec]);
      const unsigned short* urp = (const unsigned short*)&ur;
      const unsigned short* uzp = (const unsigned short*)&uz;
      const unsigned short* unp = (const unsigned short*)&un;
      ushort4 hb;
      unsigned short* hbp = (unsigned short*)&hb;
      #pragma unroll
      for (int j = 0; j < 4; ++j){
        float R = sigm(sR[j] + bf2f(urp[j]));
        float Z = sigm(sZ[j] + bf2f(uzp[j]));
        float N = tanhf_(bf2f(unp[j]) + R * (sN[j] + bN[j]));
        float hn = N + Z * (h[j] - N);
        h[j] = hn;
        hbp[j] = f2bu(hn);
      }
      *(ushort4*)((char*)hA[nxt] + er * 512 + ((ec * 2) ^ ((er & 7) << 4))) = hb;
      size_t go = ((size_t)(grp * 8 + er) * NT + t) * 256 + ec;
      *reinterpret_cast<ushort4*>(outw + go) = hb;
      *reinterpret_cast<ushort4*>(rhw + go)  = hb;
    }
    __syncthreads();   // barrier 2: hA[nxt] + prefetch complete, sG reusable
  }
  *reinterpret_cast<f32x4*>(hfin + (size_t)(grp * 8 + er) * 256 + ec) = h;
}

// ---------------- fused refinement step ----------------
// MODE 0: out'->outw(bf16) then rh'=tanh(out'@Wu^T+bu)->rhw   (iters 0,1)
// MODE 1: out'->outw(bf16) only                               (final, layer 0)
// MODE 2: out'->dst(f32) only                                 (final, layer 1)
template<int MODE>
__global__ __launch_bounds__(1024) void refine_step(
    const unsigned short* __restrict__ outb, const unsigned short* __restrict__ rhb,
    const unsigned short* __restrict__ wgt,  const unsigned short* __restrict__ wu,
    const float* __restrict__ bg, const float* __restrict__ bt, const float* __restrict__ bu,
    unsigned short* __restrict__ outw, unsigned short* __restrict__ rhw,
    float* __restrict__ dst)
{
  __shared__ alignas(16) unsigned short sC[64 * 512];   // comb [64][1024B], swizzled
  const int tid = threadIdx.x, blk = blockIdx.x;
  const int ln = tid & 63, wv = tid >> 6, m = ln & 15, lg = ln >> 4;
  {
    #pragma unroll
    for (int i = 0; i < 4; ++i){
      int o = tid * 16 + i * 16384;
      int r = o >> 10, wb = o & 1023;
      int wb2 = wb ^ ((r & 7) << 4);
      const char* src = (wb2 < 512)
        ? (const char*)(outb + (size_t)(blk * 64 + r) * 256) + wb2
        : (const char*)(rhb  + (size_t)(blk * 64 + r) * 256) + (wb2 - 512);
      gload_lds16(src, (char*)sC + o);
    }
  }
  __syncthreads();
  f32x4 ag[4] = {}, at4[4] = {};
  #pragma unroll 2
  for (int kc = 0; kc < 16; ++kc){
    int kk = kc * 32 + lg * 8;
    bf16x8 a[4];
    #pragma unroll
    for (int mt = 0; mt < 4; ++mt){
      int row = mt * 16 + m;
      a[mt] = *(const bf16x8*)((const char*)sC + row * 1024 + ((kk * 2) ^ ((row & 7) << 4)));
    }
    bf16x8 bgf = ldG(wgt + (size_t)(wv * 16 + m) * 512 + kk);
    bf16x8 btf = ldG(wgt + (size_t)(256 + wv * 16 + m) * 512 + kk);
    #pragma unroll
    for (int mt = 0; mt < 4; ++mt){
      ag[mt]  = MFMA(a[mt], bgf, ag[mt]);
      at4[mt] = MFMA(a[mt], btf, at4[mt]);
    }
  }
  const int c = wv * 16 + m;
  float bgv = bg[c], btv = bt[c];
  __syncthreads();  // all GEMM1 reads of sC done (rh half becomes scratch)
  #pragma unroll
  for (int mt = 0; mt < 4; ++mt){
    #pragma unroll
    for (int j = 0; j < 4; ++j){
      int rowl = mt * 16 + lg * 4 + j;
      float g  = sigm(ag[mt][j] + bgv);
      float rf = tanhf_(at4[mt][j] + btv);
      float old = bf2f(sC[(rowl * 1024 + ((c * 2) ^ ((rowl & 7) << 4))) >> 1]);
      float on = g * rf + (1.f - g) * old;
      size_t go = (size_t)(blk * 64 + rowl) * 256 + c;
      if (MODE == 2) dst[go] = on;
      else           outw[go] = f2bu(on);
      if (MODE == 0)  // stash out' bf16 in sC's dead rh half for GEMM2
        *(unsigned short*)((char*)sC + rowl * 1024 + 512 + ((c * 2) ^ ((rowl & 7) << 4))) = f2bu(on);
    }
  }
  if (MODE == 0){
    __syncthreads();
    f32x4 au[4] = {};
    #pragma unroll
    for (int kc = 0; kc < 8; ++kc){
      int kb = kc * 64 + lg * 16;
      bf16x8 b = ldG(wu + (size_t)c * 256 + kc * 32 + lg * 8);
      #pragma unroll
      for (int mt = 0; mt < 4; ++mt){
        int row = mt * 16 + m;
        bf16x8 a = *(const bf16x8*)((const char*)sC + row * 1024 + 512 + (kb ^ ((row & 7) << 4)));
        au[mt] = MFMA(a, b, au[mt]);
      }
    }
    float buv = bu[c];
    #pragma unroll
    for (int mt = 0; mt < 4; ++mt){
      #pragma unroll
      for (int j = 0; j < 4; ++j){
        int rowl = mt * 16 + lg * 4 + j;
        rhw[(size_t)(blk * 64 + rowl) * 256 + c] = f2bu(tanhf_(au[mt][j] + buv));
      }
    }
  }
}

extern "C" void kernel_launch(void* const* d_in, const int* in_sizes, int n_in,
                              void* d_out, int out_size, void* d_ws, size_t ws_size,
                              hipStream_t stream) {
  const float* x   = (const float*)d_in[0];
  const float* Wih = (const float*)d_in[1];
  const float* bih = (const float*)d_in[2];
  const float* Whh = (const float*)d_in[3];
  const float* bhh = (const float*)d_in[4];
  const float* Wg  = (const float*)d_in[5];
  const float* bg  = (const float*)d_in[6];
  const float* Wt  = (const float*)d_in[7];
  const float* bt  = (const float*)d_in[8];
  const float* Wu  = (const float*)d_in[9];
  const float* bu  = (const float*)d_in[10];
  unsigned short* ws = (unsigned short*)d_ws;
  float* o  = (float*)d_out;
  float* hf = o + (size_t)NB * NT * NH;

  unsigned short* xin  = ws + OFF_XIN;
  unsigned short* gi   = ws + OFF_GI;
  unsigned short* outb = ws + OFF_OUT;
  unsigned short* rhb  = ws + OFF_RH;

  cvt_weights<<<W_TOTAL / 256, 256, 0, stream>>>(Wih, Whh, Wg, Wt, Wu, ws);
  pack_x<<<(NROW * 256 / 4) / 256, 256, 0, stream>>>(x, xin);

  for (int l = 0; l < 2; ++l){
    const unsigned short* wih = ws + OFF_WIH + (size_t)l * 768 * 256;
    const unsigned short* whh = ws + OFF_WHH + (size_t)l * 768 * 256;
    const unsigned short* wgt = ws + OFF_WGT + (size_t)l * 512 * 512;
    const unsigned short* wu  = ws + OFF_WU  + (size_t)l * 256 * 256;

    gi_gemm<<<512, 1024, 0, stream>>>(l == 0 ? xin : outb, wih,
                                      bih + l * 768, bhh + l * 768, gi);
    chain<<<8, 512, 0, stream>>>(gi, whh, bhh + l * 768, outb, rhb, hf + (size_t)l * NB * NH);
    refine_step<0><<<512, 1024, 0, stream>>>(outb, rhb, wgt, wu,
        bg + l * 256, bt + l * 256, bu + l * 256, outb, rhb, nullptr);
    refine_step<0><<<512, 1024, 0, stream>>>(outb, rhb, wgt, wu,
        bg + l * 256, bt + l * 256, bu + l * 256, outb, rhb, nullptr);
    if (l == 0)
      refine_step<1><<<512, 1024, 0, stream>>>(outb, rhb, wgt, wu,
          bg + l * 256, bt + l * 256, bu + l * 256, outb, rhb, nullptr);
    else
      refine_step<2><<<512, 1024, 0, stream>>>(outb, rhb, wgt, wu,
          bg + l * 256, bt + l * 256, bu + l * 256, nullptr, nullptr, o);
  }
}

// Round 4
// 2172.928 us; speedup vs baseline: 36.5701x; 1.3785x over previous
//
#include <hip/hip_runtime.h>

typedef float  f32x4  __attribute__((ext_vector_type(4)));
typedef __bf16 bf16x8 __attribute__((ext_vector_type(8)));

#define NB 64
#define NT 512
#define ND 256
#define NH 256
#define NROW (NB*NT)   // 32768

// ws ushort offsets
#define OFF_WIH 0
#define OFF_WHH 393216
#define OFF_WGT 786432          // [l][512][512]: rows 0-255 Wg, 256-511 Wt
#define OFF_WU  1310720
#define W_TOTAL 1441792
#define OFF_XIN (W_TOTAL)                   // [32768][256] bf16 (b-major)
#define OFF_GI  (OFF_XIN + NROW*256)        // [512][64][768] bf16, t-major
#define OFF_OUT (OFF_GI + 512*64*768)       // [32768][256] bf16
#define OFF_RH  (OFF_OUT + NROW*256)        // [32768][256] bf16

__device__ inline unsigned short f2bu(float f){
  unsigned int u = __builtin_bit_cast(unsigned int, f);
  unsigned int r = u + 0x7fffu + ((u >> 16) & 1u);
  return (unsigned short)(r >> 16);
}
__device__ inline float bf2f(unsigned short u){
  unsigned int v = ((unsigned int)u) << 16;
  return __builtin_bit_cast(float, v);
}
__device__ inline float sigm(float x){ return 1.0f / (1.0f + __expf(-x)); }
__device__ inline float tanhf_(float x){ return 1.0f - 2.0f / (__expf(2.0f * x) + 1.0f); }

#define MFMA(a,b,c) __builtin_amdgcn_mfma_f32_16x16x32_bf16((a),(b),(c),0,0,0)

__device__ inline void gload_lds16(const void* g, void* l){
  __builtin_amdgcn_global_load_lds(
    (const __attribute__((address_space(1))) unsigned int*)g,
    (__attribute__((address_space(3))) unsigned int*)l, 16, 0, 0);
}
__device__ inline bf16x8 ldG(const unsigned short* p){
  return *reinterpret_cast<const bf16x8*>(p);
}

// ---------------- weight / input packing ----------------
__global__ void cvt_weights(const float* __restrict__ Wih, const float* __restrict__ Whh,
                            const float* __restrict__ Wg,  const float* __restrict__ Wt,
                            const float* __restrict__ Wu,  unsigned short* __restrict__ ws){
  int i = blockIdx.x * blockDim.x + threadIdx.x;
  if (i < OFF_WHH) {
    ws[i] = f2bu(Wih[i]);
  } else if (i < OFF_WGT) {
    ws[i] = f2bu(Whh[i - OFF_WHH]);
  } else if (i < OFF_WU) {
    int j = i - OFF_WGT;
    int l = j >> 18; int r = (j >> 9) & 511; int k = j & 511;
    float v = (r < 256) ? Wg[(l * 256 + r) * 512 + k]
                        : Wt[(l * 256 + (r - 256)) * 512 + k];
    ws[i] = f2bu(v);
  } else if (i < W_TOTAL) {
    ws[i] = f2bu(Wu[i - OFF_WU]);
  }
}

__global__ void pack_x(const float* __restrict__ x, unsigned short* __restrict__ xin){
  size_t i = ((size_t)blockIdx.x * blockDim.x + threadIdx.x) * 4;
  float4 v = *reinterpret_cast<const float4*>(x + i);
  ushort4 u; u.x = f2bu(v.x); u.y = f2bu(v.y); u.z = f2bu(v.z); u.w = f2bu(v.w);
  *reinterpret_cast<ushort4*>(xin + i) = u;
}

// ---------------- GI = in @ Wih^T + (bih [+ bhh for r,z]) ----------------
__global__ __launch_bounds__(1024) void gi_gemm(
    const unsigned short* __restrict__ xin,  // [NROW][256] bf16 (b-major)
    const unsigned short* __restrict__ wih,  // [768][256]
    const float* __restrict__ bih, const float* __restrict__ bhh,
    unsigned short* __restrict__ gi)         // [512][64][768] t-major
{
  __shared__ alignas(16) unsigned short sA[64 * 256];
  const int tid = threadIdx.x, blk = blockIdx.x;
  const int ln = tid & 63, wv = tid >> 6, m = ln & 15, lg = ln >> 4;
  {
    const char* src = (const char*)(xin + (size_t)blk * 64 * 256);
    #pragma unroll
    for (int i = 0; i < 2; ++i){
      int o = tid * 16 + i * 16384;
      int r = o >> 9, wb = o & 511;
      gload_lds16(src + (size_t)r * 512 + (wb ^ ((r & 7) << 4)), (char*)sA + o);
    }
  }
  __syncthreads();
  f32x4 acc[3][4] = {};
  #pragma unroll
  for (int kc = 0; kc < 8; ++kc){
    int kk = kc * 32 + lg * 8;
    bf16x8 a[4];
    #pragma unroll
    for (int mt = 0; mt < 4; ++mt){
      int row = mt * 16 + m;
      a[mt] = *(const bf16x8*)((const char*)sA + row * 512 + ((kk * 2) ^ ((row & 7) << 4)));
    }
    #pragma unroll
    for (int g = 0; g < 3; ++g){
      bf16x8 b = ldG(wih + (size_t)(g * 256 + wv * 16 + m) * 256 + kk);
      #pragma unroll
      for (int mt = 0; mt < 4; ++mt) acc[g][mt] = MFMA(a[mt], b, acc[g][mt]);
    }
  }
  const int c = wv * 16 + m;
  #pragma unroll
  for (int g = 0; g < 3; ++g){
    float bias = bih[g * 256 + c] + (g < 2 ? bhh[g * 256 + c] : 0.f);
    #pragma unroll
    for (int mt = 0; mt < 4; ++mt){
      #pragma unroll
      for (int j = 0; j < 4; ++j){
        int row = blk * 64 + mt * 16 + lg * 4 + j;
        int b = row >> 9, t = row & 511;
        gi[((size_t)t * 64 + b) * 768 + g * 256 + c] = f2bu(acc[g][mt][j] + bias);
      }
    }
  }
}

// ---------------- sequential GRU chain ----------------
// grid 8 x 512 thr (8 waves). Operand-swapped MFMA: D = Whh_tile @ h^T, so each
// wave owns 32 output cols for ALL THREE gates -> lane-local epilogue, ONE
// barrier per step. h duplicated into B-rows 8-15 so all 64 lanes finalize.
__global__ __launch_bounds__(512, 2) void chain(
    const unsigned short* __restrict__ gi,   // [512][64][768]
    const unsigned short* __restrict__ whh,  // [768][256]
    const float* __restrict__ bhh,           // [768] (n-gate bias used)
    unsigned short* __restrict__ outw,       // [NROW][256]
    float* __restrict__ hfin)                // [64][256] this layer
{
  __shared__ alignas(16) unsigned short hA[2][16 * 256];   // 8KB each, 512B rows XOR-swz
  __shared__ alignas(16) unsigned short sGI[2][8 * 768];   // 12KB each, 512B gate-rows XOR-swz
  const int tid = threadIdx.x, grp = blockIdx.x;
  const int ln  = tid & 63, wv = tid >> 6;
  const int m   = ln & 15;           // A-frag row / B-frag row (batch, dup at 8-15)
  const int lg  = ln >> 4;           // k sub-block
  const int rr  = ln & 7;            // epilogue batch row
  const int sown = (ln >> 3) & 1;    // which 16-col subtile this lane finalizes

  // resident Whh fragments: tile (g,s) rows g*256 + wv*32 + s*16 + m
  f32x4 wf[3][2][8];
  #pragma unroll
  for (int g = 0; g < 3; ++g)
    #pragma unroll
    for (int s = 0; s < 2; ++s){
      const unsigned short* p = whh + (size_t)(g * 256 + wv * 32 + s * 16 + m) * 256;
      #pragma unroll
      for (int kc = 0; kc < 8; ++kc){
        wf[g][s][kc] = *reinterpret_cast<const f32x4*>(p + kc * 32 + lg * 8);
        asm volatile("" : "+v"(wf[g][s][kc]));
      }
    }

  const int colq = wv * 32 + sown * 16 + lg * 4;           // lane's first col
  f32x4 bN = *reinterpret_cast<const f32x4*>(bhh + 512 + colq);

  // zero both h buffers
  *reinterpret_cast<uint4*>((char*)hA[0] + tid * 16) = uint4{0,0,0,0};
  *reinterpret_cast<uint4*>((char*)hA[1] + tid * 16) = uint4{0,0,0,0};

  auto stage = [&](int buf, int t){
    const char* src = (const char*)gi + ((size_t)t * 64 + grp * 8) * 1536;
    {
      int o = tid * 16;
      int sw = (o & 511) ^ (((o >> 9) & 7) << 4);
      gload_lds16(src + (o & ~511) + sw, (char*)sGI[buf] + o);
    }
    if (tid < 256){
      int o = 8192 + tid * 16;
      int sw = (o & 511) ^ (((o >> 9) & 7) << 4);
      gload_lds16(src + (o & ~511) + sw, (char*)sGI[buf] + o);
    }
  };
  stage(0, 0);
  f32x4 h = {0.f, 0.f, 0.f, 0.f};
  __syncthreads();

  for (int t = 0; t < NT; ++t){
    const int cur = t & 1, nxt = cur ^ 1;
    if (t + 1 < NT) stage(nxt, t + 1);   // in flight across whole step, drained at barrier

    f32x4 acc[3][2] = {};
    #pragma unroll
    for (int kc = 0; kc < 8; ++kc){
      int kb = kc * 64 + lg * 16;   // byte offset of k-slice in 512B row
      bf16x8 hv = *(const bf16x8*)((const char*)hA[cur] + m * 512 + (kb ^ ((m & 7) << 4)));
      #pragma unroll
      for (int g = 0; g < 3; ++g){
        acc[g][0] = MFMA(__builtin_bit_cast(bf16x8, wf[g][0][kc]), hv, acc[g][0]);
        acc[g][1] = MFMA(__builtin_bit_cast(bf16x8, wf[g][1][kc]), hv, acc[g][1]);
      }
    }

    // lane-local epilogue: (row rr, cols colq..colq+3), gates from sGI
    {
      const int colb = colq * 2;
      auto ldGI = [&](int gate) -> ushort4 {
        int r512 = rr * 3 + gate;
        int addr = r512 * 512 + (colb ^ ((r512 & 7) << 4));
        return *reinterpret_cast<const ushort4*>((const char*)sGI[cur] + addr);
      };
      ushort4 ur = ldGI(0), uz = ldGI(1), un = ldGI(2);
      f32x4 aR = sown ? acc[0][1] : acc[0][0];
      f32x4 aZ = sown ? acc[1][1] : acc[1][0];
      f32x4 aN = sown ? acc[2][1] : acc[2][0];
      const unsigned short* urp = (const unsigned short*)&ur;
      const unsigned short* uzp = (const unsigned short*)&uz;
      const unsigned short* unp = (const unsigned short*)&un;
      ushort4 hb; unsigned short* hbp = (unsigned short*)&hb;
      #pragma unroll
      for (int j = 0; j < 4; ++j){
        float R = sigm(aR[j] + bf2f(urp[j]));
        float Z = sigm(aZ[j] + bf2f(uzp[j]));
        float N = tanhf_(bf2f(unp[j]) + R * (aN[j] + bN[j]));
        float hn = N + Z * (h[j] - N);
        h[j] = hn;
        hbp[j] = f2bu(hn);
      }
      const int wb = colb ^ ((rr & 7) << 4);
      *(ushort4*)((char*)hA[nxt] + rr * 512 + wb) = hb;          // rows rr and rr+8
      *(ushort4*)((char*)hA[nxt] + (rr + 8) * 512 + wb) = hb;    // (same swizzle key)
      *reinterpret_cast<ushort4*>(outw + ((size_t)(grp * 8 + rr) * NT + t) * 256 + colq) = hb;
    }
    __syncthreads();   // hA[nxt] + sGI[nxt] ready; sGI[cur]/hA[cur] reusable
  }
  *reinterpret_cast<f32x4*>(hfin + (size_t)(grp * 8 + rr) * 256 + colq) = h;
}

// ---------------- fused refinement step ----------------
// MODE 0: out'->outw(bf16) then rh'=tanh(out'@Wu^T+bu)->rhw   (iters 0,1)
// MODE 1: out'->outw(bf16) only                               (final, layer 0)
// MODE 2: out'->dst(f32) only                                 (final, layer 1)
template<int MODE>
__global__ __launch_bounds__(1024) void refine_step(
    const unsigned short* __restrict__ outb, const unsigned short* __restrict__ rhb,
    const unsigned short* __restrict__ wgt,  const unsigned short* __restrict__ wu,
    const float* __restrict__ bg, const float* __restrict__ bt, const float* __restrict__ bu,
    unsigned short* __restrict__ outw, unsigned short* __restrict__ rhw,
    float* __restrict__ dst)
{
  __shared__ alignas(16) unsigned short sC[64 * 512];   // comb [64][1024B], swizzled
  const int tid = threadIdx.x, blk = blockIdx.x;
  const int ln = tid & 63, wv = tid >> 6, m = ln & 15, lg = ln >> 4;
  {
    #pragma unroll
    for (int i = 0; i < 4; ++i){
      int o = tid * 16 + i * 16384;
      int r = o >> 10, wb = o & 1023;
      int wb2 = wb ^ ((r & 7) << 4);
      const char* src = (wb2 < 512)
        ? (const char*)(outb + (size_t)(blk * 64 + r) * 256) + wb2
        : (const char*)(rhb  + (size_t)(blk * 64 + r) * 256) + (wb2 - 512);
      gload_lds16(src, (char*)sC + o);
    }
  }
  __syncthreads();
  f32x4 ag[4] = {}, at4[4] = {};
  #pragma unroll 2
  for (int kc = 0; kc < 16; ++kc){
    int kk = kc * 32 + lg * 8;
    bf16x8 a[4];
    #pragma unroll
    for (int mt = 0; mt < 4; ++mt){
      int row = mt * 16 + m;
      a[mt] = *(const bf16x8*)((const char*)sC + row * 1024 + ((kk * 2) ^ ((row & 7) << 4)));
    }
    bf16x8 bgf = ldG(wgt + (size_t)(wv * 16 + m) * 512 + kk);
    bf16x8 btf = ldG(wgt + (size_t)(256 + wv * 16 + m) * 512 + kk);
    #pragma unroll
    for (int mt = 0; mt < 4; ++mt){
      ag[mt]  = MFMA(a[mt], bgf, ag[mt]);
      at4[mt] = MFMA(a[mt], btf, at4[mt]);
    }
  }
  const int c = wv * 16 + m;
  float bgv = bg[c], btv = bt[c];
  __syncthreads();  // all GEMM1 reads of sC done (rh half becomes scratch)
  #pragma unroll
  for (int mt = 0; mt < 4; ++mt){
    #pragma unroll
    for (int j = 0; j < 4; ++j){
      int rowl = mt * 16 + lg * 4 + j;
      float g  = sigm(ag[mt][j] + bgv);
      float rf = tanhf_(at4[mt][j] + btv);
      float old = bf2f(sC[(rowl * 1024 + ((c * 2) ^ ((rowl & 7) << 4))) >> 1]);
      float on = g * rf + (1.f - g) * old;
      size_t go = (size_t)(blk * 64 + rowl) * 256 + c;
      if (MODE == 2) dst[go] = on;
      else           outw[go] = f2bu(on);
      if (MODE == 0)  // stash out' bf16 in sC's dead rh half for GEMM2
        *(unsigned short*)((char*)sC + rowl * 1024 + 512 + ((c * 2) ^ ((rowl & 7) << 4))) = f2bu(on);
    }
  }
  if (MODE == 0){
    __syncthreads();
    f32x4 au[4] = {};
    #pragma unroll
    for (int kc = 0; kc < 8; ++kc){
      int kb = kc * 64 + lg * 16;
      bf16x8 b = ldG(wu + (size_t)c * 256 + kc * 32 + lg * 8);
      #pragma unroll
      for (int mt = 0; mt < 4; ++mt){
        int row = mt * 16 + m;
        bf16x8 a = *(const bf16x8*)((const char*)sC + row * 1024 + 512 + (kb ^ ((row & 7) << 4)));
        au[mt] = MFMA(a, b, au[mt]);
      }
    }
    float buv = bu[c];
    #pragma unroll
    for (int mt = 0; mt < 4; ++mt){
      #pragma unroll
      for (int j = 0; j < 4; ++j){
        int rowl = mt * 16 + lg * 4 + j;
        rhw[(size_t)(blk * 64 + rowl) * 256 + c] = f2bu(tanhf_(au[mt][j] + buv));
      }
    }
  }
}

extern "C" void kernel_launch(void* const* d_in, const int* in_sizes, int n_in,
                              void* d_out, int out_size, void* d_ws, size_t ws_size,
                              hipStream_t stream) {
  const float* x   = (const float*)d_in[0];
  const float* Wih = (const float*)d_in[1];
  const float* bih = (const float*)d_in[2];
  const float* Whh = (const float*)d_in[3];
  const float* bhh = (const float*)d_in[4];
  const float* Wg  = (const float*)d_in[5];
  const float* bg  = (const float*)d_in[6];
  const float* Wt  = (const float*)d_in[7];
  const float* bt  = (const float*)d_in[8];
  const float* Wu  = (const float*)d_in[9];
  const float* bu  = (const float*)d_in[10];
  unsigned short* ws = (unsigned short*)d_ws;
  float* o  = (float*)d_out;
  float* hf = o + (size_t)NB * NT * NH;

  unsigned short* xin  = ws + OFF_XIN;
  unsigned short* gi   = ws + OFF_GI;
  unsigned short* outb = ws + OFF_OUT;
  unsigned short* rhb  = ws + OFF_RH;

  cvt_weights<<<W_TOTAL / 256, 256, 0, stream>>>(Wih, Whh, Wg, Wt, Wu, ws);
  pack_x<<<(NROW * 256 / 4) / 256, 256, 0, stream>>>(x, xin);

  for (int l = 0; l < 2; ++l){
    const unsigned short* wih = ws + OFF_WIH + (size_t)l * 768 * 256;
    const unsigned short* whh = ws + OFF_WHH + (size_t)l * 768 * 256;
    const unsigned short* wgt = ws + OFF_WGT + (size_t)l * 512 * 512;
    const unsigned short* wu  = ws + OFF_WU  + (size_t)l * 256 * 256;

    gi_gemm<<<512, 1024, 0, stream>>>(l == 0 ? xin : outb, wih,
                                      bih + l * 768, bhh + l * 768, gi);
    chain<<<8, 512, 0, stream>>>(gi, whh, bhh + l * 768, outb, hf + (size_t)l * NB * NH);
    // refinement iter 0: rh == out (chain writes only outb), so pass outb twice
    refine_step<0><<<512, 1024, 0, stream>>>(outb, outb, wgt, wu,
        bg + l * 256, bt + l * 256, bu + l * 256, outb, rhb, nullptr);
    refine_step<0><<<512, 1024, 0, stream>>>(outb, rhb, wgt, wu,
        bg + l * 256, bt + l * 256, bu + l * 256, outb, rhb, nullptr);
    if (l == 0)
      refine_step<1><<<512, 1024, 0, stream>>>(outb, rhb, wgt, wu,
          bg + l * 256, bt + l * 256, bu + l * 256, outb, rhb, nullptr);
    else
      refine_step<2><<<512, 1024, 0, stream>>>(outb, rhb, wgt, wu,
          bg + l * 256, bt + l * 256, bu + l * 256, nullptr, nullptr, o);
  }
}

// Round 5
// 1458.063 us; speedup vs baseline: 54.4999x; 1.4903x over previous
//
#include <hip/hip_runtime.h>

typedef float  f32x4  __attribute__((ext_vector_type(4)));
typedef __bf16 bf16x8 __attribute__((ext_vector_type(8)));

#define NB 64
#define NT 512
#define ND 256
#define NH 256
#define NROW (NB*NT)   // 32768

// ws ushort offsets
#define OFF_WIH 0
#define OFF_WHH 393216
#define OFF_WGT 786432          // [l][512][512]: rows 0-255 Wg, 256-511 Wt
#define OFF_WU  1310720
#define W_TOTAL 1441792
#define OFF_XIN (W_TOTAL)                   // [32768][256] bf16 (b-major)
#define OFF_GI  (OFF_XIN + NROW*256)        // [512][64][768] bf16, t-major
#define OFF_OUT (OFF_GI + 512*64*768)       // [32768][256] bf16
#define OFF_RH  (OFF_OUT + NROW*256)        // [32768][256] bf16

__device__ inline unsigned short f2bu(float f){
  unsigned int u = __builtin_bit_cast(unsigned int, f);
  unsigned int r = u + 0x7fffu + ((u >> 16) & 1u);
  return (unsigned short)(r >> 16);
}
__device__ inline float bf2f(unsigned short u){
  unsigned int v = ((unsigned int)u) << 16;
  return __builtin_bit_cast(float, v);
}
__device__ inline float sigm(float x){ return 1.0f / (1.0f + __expf(-x)); }
__device__ inline float tanhf_(float x){ return 1.0f - 2.0f / (__expf(2.0f * x) + 1.0f); }

#define MFMA(a,b,c) __builtin_amdgcn_mfma_f32_16x16x32_bf16((a),(b),(c),0,0,0)

__device__ inline void gload_lds16(const void* g, void* l){
  __builtin_amdgcn_global_load_lds(
    (const __attribute__((address_space(1))) unsigned int*)g,
    (__attribute__((address_space(3))) unsigned int*)l, 16, 0, 0);
}
__device__ inline bf16x8 ldG(const unsigned short* p){
  return *reinterpret_cast<const bf16x8*>(p);
}

// ---------------- weight / input packing ----------------
__global__ void cvt_weights(const float* __restrict__ Wih, const float* __restrict__ Whh,
                            const float* __restrict__ Wg,  const float* __restrict__ Wt,
                            const float* __restrict__ Wu,  unsigned short* __restrict__ ws){
  int i = blockIdx.x * blockDim.x + threadIdx.x;
  if (i < OFF_WHH) {
    ws[i] = f2bu(Wih[i]);
  } else if (i < OFF_WGT) {
    ws[i] = f2bu(Whh[i - OFF_WHH]);
  } else if (i < OFF_WU) {
    int j = i - OFF_WGT;
    int l = j >> 18; int r = (j >> 9) & 511; int k = j & 511;
    float v = (r < 256) ? Wg[(l * 256 + r) * 512 + k]
                        : Wt[(l * 256 + (r - 256)) * 512 + k];
    ws[i] = f2bu(v);
  } else if (i < W_TOTAL) {
    ws[i] = f2bu(Wu[i - OFF_WU]);
  }
}

__global__ void pack_x(const float* __restrict__ x, unsigned short* __restrict__ xin){
  size_t i = ((size_t)blockIdx.x * blockDim.x + threadIdx.x) * 4;
  float4 v = *reinterpret_cast<const float4*>(x + i);
  ushort4 u; u.x = f2bu(v.x); u.y = f2bu(v.y); u.z = f2bu(v.z); u.w = f2bu(v.w);
  *reinterpret_cast<ushort4*>(xin + i) = u;
}

// ---------------- GI = in @ Wih^T + (bih [+ bhh for r,z]) ----------------
__global__ __launch_bounds__(1024) void gi_gemm(
    const unsigned short* __restrict__ xin,  // [NROW][256] bf16 (b-major)
    const unsigned short* __restrict__ wih,  // [768][256]
    const float* __restrict__ bih, const float* __restrict__ bhh,
    unsigned short* __restrict__ gi)         // [512][64][768] t-major
{
  __shared__ alignas(16) unsigned short sA[64 * 256];
  const int tid = threadIdx.x, blk = blockIdx.x;
  const int ln = tid & 63, wv = tid >> 6, m = ln & 15, lg = ln >> 4;
  {
    const char* src = (const char*)(xin + (size_t)blk * 64 * 256);
    #pragma unroll
    for (int i = 0; i < 2; ++i){
      int o = tid * 16 + i * 16384;
      int r = o >> 9, wb = o & 511;
      gload_lds16(src + (size_t)r * 512 + (wb ^ ((r & 7) << 4)), (char*)sA + o);
    }
  }
  __syncthreads();
  f32x4 acc[3][4] = {};
  #pragma unroll
  for (int kc = 0; kc < 8; ++kc){
    int kk = kc * 32 + lg * 8;
    bf16x8 a[4];
    #pragma unroll
    for (int mt = 0; mt < 4; ++mt){
      int row = mt * 16 + m;
      a[mt] = *(const bf16x8*)((const char*)sA + row * 512 + ((kk * 2) ^ ((row & 7) << 4)));
    }
    #pragma unroll
    for (int g = 0; g < 3; ++g){
      bf16x8 b = ldG(wih + (size_t)(g * 256 + wv * 16 + m) * 256 + kk);
      #pragma unroll
      for (int mt = 0; mt < 4; ++mt) acc[g][mt] = MFMA(a[mt], b, acc[g][mt]);
    }
  }
  const int c = wv * 16 + m;
  #pragma unroll
  for (int g = 0; g < 3; ++g){
    float bias = bih[g * 256 + c] + (g < 2 ? bhh[g * 256 + c] : 0.f);
    #pragma unroll
    for (int mt = 0; mt < 4; ++mt){
      #pragma unroll
      for (int j = 0; j < 4; ++j){
        int row = blk * 64 + mt * 16 + lg * 4 + j;
        int b = row >> 9, t = row & 511;
        gi[((size_t)t * 64 + b) * 768 + g * 256 + c] = f2bu(acc[g][mt][j] + bias);
      }
    }
  }
}

// ---------------- sequential GRU chain ----------------
// grid 32 (2 batch rows each), block 512 (8 waves). Whh register-resident.
// MFMA(h_frag, W_frag): D[batch][wcol]; lane owns ONE (batch,wcol) output.
// Gates prefetched per-lane from global, distance 2. Raw barrier (lgkmcnt only)
// so gate loads / out stores ride across steps.
__global__ __launch_bounds__(512, 2) void chain(
    const unsigned short* __restrict__ gi,   // [512][64][768]
    const unsigned short* __restrict__ whh,  // [768][256]
    const float* __restrict__ bhh,           // [768] (n-gate bias used)
    unsigned short* __restrict__ outw,       // [NROW][256]
    float* __restrict__ hfin)                // [64][256] this layer
{
  __shared__ alignas(16) unsigned short hA[2][2 * 256];  // 2 buffers x 2 rows x 512B
  const int tid = threadIdx.x, grp = blockIdx.x;
  const int ln  = tid & 63, wv = tid >> 6;
  const int m   = ln & 15;
  const int lg  = ln >> 4;

  // resident Whh fragments: tile (g,s): W rows g*256 + wv*32 + s*16 + m, k-slice lg
  f32x4 wf[3][2][8];
  #pragma unroll
  for (int g = 0; g < 3; ++g)
    #pragma unroll
    for (int s = 0; s < 2; ++s){
      const unsigned short* p = whh + (size_t)(g * 256 + wv * 32 + s * 16 + m) * 256;
      #pragma unroll
      for (int kc = 0; kc < 8; ++kc){
        wf[g][s][kc] = *reinterpret_cast<const f32x4*>(p + kc * 32 + lg * 8);
        asm volatile("" : "+v"(wf[g][s][kc]));
      }
    }

  const int bb   = lg & 1;                    // lane's batch row (0/1)
  const int su   = lg >> 1;                   // lane's subtile
  const int wcol = wv * 32 + su * 16 + m;     // lane's output column
  const int brow = grp * 2 + bb;              // global batch row
  const float bNv = bhh[512 + wcol];

  const int  arow  = m & 1;                   // A-fragment batch row
  const int  arows = arow << 4;               // its swizzle key
  char* hAc = (char*)hA;
  const int rbase = arow * 512;               // read row offset
  const int wbyte = bb * 512 + ((wcol * 2) ^ (bb << 4));  // write offset in buffer

  const unsigned short* gbase = gi + (size_t)brow * 768 + wcol;
  unsigned short* op = outw + (size_t)brow * NT * 256 + wcol;

  if (tid < 256){
    ((unsigned int*)hA[0])[tid] = 0;
    ((unsigned int*)hA[1])[tid] = 0;
  }
  // preload gates for t=0,1
  unsigned int gAr = gbase[0], gAz = gbase[256], gAn = gbase[512];
  unsigned int gBr = gbase[49152], gBz = gbase[49152 + 256], gBn = gbase[49152 + 512];
  float h = 0.f;
  __syncthreads();

  auto body = [&](int t, int curo, unsigned int& GR, unsigned int& GZ, unsigned int& GN){
    // copy current gate values, then reuse regs for the t+2 prefetch
    float xr = bf2f((unsigned short)GR);
    float xz = bf2f((unsigned short)GZ);
    float xn = bf2f((unsigned short)GN);
    if (t + 2 < NT){
      const unsigned short* gp = gbase + (size_t)(t + 2) * 49152;
      GR = gp[0]; GZ = gp[256]; GN = gp[512];
    }
    f32x4 a00{}, a01{}, a10{}, a11{}, a20{}, a21{};
    #pragma unroll
    for (int kc = 0; kc < 8; ++kc){
      int kb = kc * 64 + lg * 16;
      bf16x8 hv = *(const bf16x8*)(hAc + curo + rbase + (kb ^ arows));
      a00 = MFMA(hv, __builtin_bit_cast(bf16x8, wf[0][0][kc]), a00);
      a01 = MFMA(hv, __builtin_bit_cast(bf16x8, wf[0][1][kc]), a01);
      a10 = MFMA(hv, __builtin_bit_cast(bf16x8, wf[1][0][kc]), a10);
      a11 = MFMA(hv, __builtin_bit_cast(bf16x8, wf[1][1][kc]), a11);
      a20 = MFMA(hv, __builtin_bit_cast(bf16x8, wf[2][0][kc]), a20);
      a21 = MFMA(hv, __builtin_bit_cast(bf16x8, wf[2][1][kc]), a21);
    }
    // lane-local epilogue: one output (brow, wcol)
    float aR = su ? (bb ? a01[1] : a01[0]) : (bb ? a00[1] : a00[0]);
    float aZ = su ? (bb ? a11[1] : a11[0]) : (bb ? a10[1] : a10[0]);
    float aN = su ? (bb ? a21[1] : a21[0]) : (bb ? a20[1] : a20[0]);
    float R = sigm(aR + xr);
    float Z = sigm(aZ + xz);
    float N = tanhf_(xn + R * (aN + bNv));
    h = N + Z * (h - N);
    unsigned short hb = f2bu(h);
    *(unsigned short*)(hAc + (curo ^ 1024) + wbyte) = hb;
    op[t * 256] = hb;
    asm volatile("s_waitcnt lgkmcnt(0)" ::: "memory");
    __builtin_amdgcn_sched_barrier(0);
    __builtin_amdgcn_s_barrier();
    __builtin_amdgcn_sched_barrier(0);
  };

  for (int tp = 0; tp < NT; tp += 2){
    body(tp,     0,    gAr, gAz, gAn);
    body(tp + 1, 1024, gBr, gBz, gBn);
  }
  hfin[(size_t)brow * 256 + wcol] = h;
}

// ---------------- fused refinement step ----------------
// MODE 0: out'->outw(bf16) then rh'=tanh(out'@Wu^T+bu)->rhw   (iters 0,1)
// MODE 1: out'->outw(bf16) only                               (final, layer 0)
// MODE 2: out'->dst(f32) only                                 (final, layer 1)
template<int MODE>
__global__ __launch_bounds__(1024) void refine_step(
    const unsigned short* __restrict__ outb, const unsigned short* __restrict__ rhb,
    const unsigned short* __restrict__ wgt,  const unsigned short* __restrict__ wu,
    const float* __restrict__ bg, const float* __restrict__ bt, const float* __restrict__ bu,
    unsigned short* __restrict__ outw, unsigned short* __restrict__ rhw,
    float* __restrict__ dst)
{
  __shared__ alignas(16) unsigned short sC[64 * 512];   // comb [64][1024B], swizzled
  const int tid = threadIdx.x, blk = blockIdx.x;
  const int ln = tid & 63, wv = tid >> 6, m = ln & 15, lg = ln >> 4;
  {
    #pragma unroll
    for (int i = 0; i < 4; ++i){
      int o = tid * 16 + i * 16384;
      int r = o >> 10, wb = o & 1023;
      int wb2 = wb ^ ((r & 7) << 4);
      const char* src = (wb2 < 512)
        ? (const char*)(outb + (size_t)(blk * 64 + r) * 256) + wb2
        : (const char*)(rhb  + (size_t)(blk * 64 + r) * 256) + (wb2 - 512);
      gload_lds16(src, (char*)sC + o);
    }
  }
  __syncthreads();
  f32x4 ag[4] = {}, at4[4] = {};
  #pragma unroll 2
  for (int kc = 0; kc < 16; ++kc){
    int kk = kc * 32 + lg * 8;
    bf16x8 a[4];
    #pragma unroll
    for (int mt = 0; mt < 4; ++mt){
      int row = mt * 16 + m;
      a[mt] = *(const bf16x8*)((const char*)sC + row * 1024 + ((kk * 2) ^ ((row & 7) << 4)));
    }
    bf16x8 bgf = ldG(wgt + (size_t)(wv * 16 + m) * 512 + kk);
    bf16x8 btf = ldG(wgt + (size_t)(256 + wv * 16 + m) * 512 + kk);
    #pragma unroll
    for (int mt = 0; mt < 4; ++mt){
      ag[mt]  = MFMA(a[mt], bgf, ag[mt]);
      at4[mt] = MFMA(a[mt], btf, at4[mt]);
    }
  }
  const int c = wv * 16 + m;
  float bgv = bg[c], btv = bt[c];
  __syncthreads();  // all GEMM1 reads of sC done (rh half becomes scratch)
  #pragma unroll
  for (int mt = 0; mt < 4; ++mt){
    #pragma unroll
    for (int j = 0; j < 4; ++j){
      int rowl = mt * 16 + lg * 4 + j;
      float g  = sigm(ag[mt][j] + bgv);
      float rf = tanhf_(at4[mt][j] + btv);
      float old = bf2f(sC[(rowl * 1024 + ((c * 2) ^ ((rowl & 7) << 4))) >> 1]);
      float on = g * rf + (1.f - g) * old;
      size_t go = (size_t)(blk * 64 + rowl) * 256 + c;
      if (MODE == 2) dst[go] = on;
      else           outw[go] = f2bu(on);
      if (MODE == 0)  // stash out' bf16 in sC's dead rh half for GEMM2
        *(unsigned short*)((char*)sC + rowl * 1024 + 512 + ((c * 2) ^ ((rowl & 7) << 4))) = f2bu(on);
    }
  }
  if (MODE == 0){
    __syncthreads();
    f32x4 au[4] = {};
    #pragma unroll
    for (int kc = 0; kc < 8; ++kc){
      int kb = kc * 64 + lg * 16;
      bf16x8 b = ldG(wu + (size_t)c * 256 + kc * 32 + lg * 8);
      #pragma unroll
      for (int mt = 0; mt < 4; ++mt){
        int row = mt * 16 + m;
        bf16x8 a = *(const bf16x8*)((const char*)sC + row * 1024 + 512 + (kb ^ ((row & 7) << 4)));
        au[mt] = MFMA(a, b, au[mt]);
      }
    }
    float buv = bu[c];
    #pragma unroll
    for (int mt = 0; mt < 4; ++mt){
      #pragma unroll
      for (int j = 0; j < 4; ++j){
        int rowl = mt * 16 + lg * 4 + j;
        rhw[(size_t)(blk * 64 + rowl) * 256 + c] = f2bu(tanhf_(au[mt][j] + buv));
      }
    }
  }
}

extern "C" void kernel_launch(void* const* d_in, const int* in_sizes, int n_in,
                              void* d_out, int out_size, void* d_ws, size_t ws_size,
                              hipStream_t stream) {
  const float* x   = (const float*)d_in[0];
  const float* Wih = (const float*)d_in[1];
  const float* bih = (const float*)d_in[2];
  const float* Whh = (const float*)d_in[3];
  const float* bhh = (const float*)d_in[4];
  const float* Wg  = (const float*)d_in[5];
  const float* bg  = (const float*)d_in[6];
  const float* Wt  = (const float*)d_in[7];
  const float* bt  = (const float*)d_in[8];
  const float* Wu  = (const float*)d_in[9];
  const float* bu  = (const float*)d_in[10];
  unsigned short* ws = (unsigned short*)d_ws;
  float* o  = (float*)d_out;
  float* hf = o + (size_t)NB * NT * NH;

  unsigned short* xin  = ws + OFF_XIN;
  unsigned short* gi   = ws + OFF_GI;
  unsigned short* outb = ws + OFF_OUT;
  unsigned short* rhb  = ws + OFF_RH;

  cvt_weights<<<W_TOTAL / 256, 256, 0, stream>>>(Wih, Whh, Wg, Wt, Wu, ws);
  pack_x<<<(NROW * 256 / 4) / 256, 256, 0, stream>>>(x, xin);

  for (int l = 0; l < 2; ++l){
    const unsigned short* wih = ws + OFF_WIH + (size_t)l * 768 * 256;
    const unsigned short* whh = ws + OFF_WHH + (size_t)l * 768 * 256;
    const unsigned short* wgt = ws + OFF_WGT + (size_t)l * 512 * 512;
    const unsigned short* wu  = ws + OFF_WU  + (size_t)l * 256 * 256;

    gi_gemm<<<512, 1024, 0, stream>>>(l == 0 ? xin : outb, wih,
                                      bih + l * 768, bhh + l * 768, gi);
    chain<<<32, 512, 0, stream>>>(gi, whh, bhh + l * 768, outb, hf + (size_t)l * NB * NH);
    // refinement iter 0: rh == out (chain writes only outb), so pass outb twice
    refine_step<0><<<512, 1024, 0, stream>>>(outb, outb, wgt, wu,
        bg + l * 256, bt + l * 256, bu + l * 256, outb, rhb, nullptr);
    refine_step<0><<<512, 1024, 0, stream>>>(outb, rhb, wgt, wu,
        bg + l * 256, bt + l * 256, bu + l * 256, outb, rhb, nullptr);
    if (l == 0)
      refine_step<1><<<512, 1024, 0, stream>>>(outb, rhb, wgt, wu,
          bg + l * 256, bt + l * 256, bu + l * 256, outb, rhb, nullptr);
    else
      refine_step<2><<<512, 1024, 0, stream>>>(outb, rhb, wgt, wu,
          bg + l * 256, bt + l * 256, bu + l * 256, nullptr, nullptr, o);
  }
}